// Round 2
// baseline (2331.239 us; speedup 1.0000x reference)
//
#include <hip/hip_runtime.h>

#define B_ 2
#define T_ 2048
#define D_ 2048
#define H_ 16
#define CONV_DIM_ 6144

typedef __bf16 bf16;
typedef bf16 bf16x8 __attribute__((ext_vector_type(8)));
typedef bf16 bf16x4 __attribute__((ext_vector_type(4)));
typedef float floatx4 __attribute__((ext_vector_type(4)));

// ---------------- elementwise f32 -> bf16 ----------------
__global__ void cvt_bf16_kernel(const float* __restrict__ in, bf16* __restrict__ out, int n4) {
    int i = blockIdx.x * 256 + threadIdx.x;
    if (i < n4) {
        float4 v = ((const float4*)in)[i];
        bf16x4 o = { (bf16)v.x, (bf16)v.y, (bf16)v.z, (bf16)v.w };
        *(bf16x4*)(out + 4 * (size_t)i) = o;
    }
}

// ---------------- transpose f32 [R,Cn] -> bf16 [Cn,R] ----------------
__global__ void transpose_kernel(const float* __restrict__ in, bf16* __restrict__ out, int R, int Cn) {
    __shared__ float tile[32][33];
    const int c0 = blockIdx.x << 5, r0 = blockIdx.y << 5;
    const int tx = threadIdx.x & 31, ty = threadIdx.x >> 5;
#pragma unroll
    for (int i = 0; i < 4; ++i) {
        int r = ty + (i << 3);
        tile[r][tx] = in[(size_t)(r0 + r) * Cn + c0 + tx];
    }
    __syncthreads();
#pragma unroll
    for (int i = 0; i < 4; ++i) {
        int cc = ty + (i << 3);
        out[(size_t)(c0 + cc) * R + r0 + tx] = (bf16)tile[tx][cc];
    }
}

// ---------------- bf16 MFMA GEMM: A[M,K] x Bt[N,K] -> C[M,N] ----------------
// 128x128 block tile, 4 waves (2x2 of 64x64), BK=64, XOR-swizzled LDS.
template <typename OutT>
__global__ __launch_bounds__(256) void gemm_kernel(
    const bf16* __restrict__ A, const bf16* __restrict__ Bt, OutT* __restrict__ C,
    int M, int N, int K) {
    __shared__ bf16 As[128 * 64];
    __shared__ bf16 Bs[128 * 64];
    const int tid = threadIdx.x;
    const int m0 = blockIdx.y << 7;
    const int n0 = blockIdx.x << 7;
    const int wave = tid >> 6, lane = tid & 63;
    const int wm = (wave >> 1) << 6, wn = (wave & 1) << 6;
    const int lrow = lane & 15, quad = lane >> 4;

    floatx4 acc[4][4];
#pragma unroll
    for (int mt = 0; mt < 4; ++mt)
#pragma unroll
        for (int nt = 0; nt < 4; ++nt)
            acc[mt][nt] = floatx4{0.f, 0.f, 0.f, 0.f};

    for (int k0 = 0; k0 < K; k0 += 64) {
        __syncthreads();
#pragma unroll
        for (int i = 0; i < 4; ++i) {
            int idx = (i << 8) + tid;
            int r = idx >> 3, c8 = idx & 7;
            int u = c8 ^ (r & 7);  // XOR swizzle on 16B units
            *(uint4*)(&As[(r << 6) + (u << 3)]) = *(const uint4*)(A + (size_t)(m0 + r) * K + k0 + (c8 << 3));
            *(uint4*)(&Bs[(r << 6) + (u << 3)]) = *(const uint4*)(Bt + (size_t)(n0 + r) * K + k0 + (c8 << 3));
        }
        __syncthreads();
#pragma unroll
        for (int kk = 0; kk < 64; kk += 32) {
            const int sw = (((kk >> 3) + quad) ^ (lrow & 7)) << 3;
            bf16x8 af[4], bfr[4];
#pragma unroll
            for (int mt = 0; mt < 4; ++mt) {
                af[mt]  = *(const bf16x8*)(&As[((wm + (mt << 4) + lrow) << 6) + sw]);
                bfr[mt] = *(const bf16x8*)(&Bs[((wn + (mt << 4) + lrow) << 6) + sw]);
            }
#pragma unroll
            for (int mt = 0; mt < 4; ++mt)
#pragma unroll
                for (int nt = 0; nt < 4; ++nt)
                    acc[mt][nt] = __builtin_amdgcn_mfma_f32_16x16x32_bf16(af[mt], bfr[nt], acc[mt][nt], 0, 0, 0);
        }
    }
    // C/D layout: col = lane&15, row = quad*4 + i  (m89/m91-verified)
#pragma unroll
    for (int mt = 0; mt < 4; ++mt)
#pragma unroll
        for (int nt = 0; nt < 4; ++nt) {
            const int col = n0 + wn + (nt << 4) + lrow;
            const int rowb = m0 + wm + (mt << 4) + (quad << 2);
#pragma unroll
            for (int i2 = 0; i2 < 4; ++i2)
                C[(size_t)(rowb + i2) * N + col] = (OutT)acc[mt][nt][i2];
        }
}

// ---------------- depthwise causal conv (K=4) + silu + split + l2norm ----------------
// grid (48, B*T), block 128. slices: 0-15 q(heads), 16-31 k, 32-47 v
__global__ void conv_silu_kernel(const bf16* __restrict__ mixed, const float* __restrict__ cw,
                                 float* __restrict__ qb, float* __restrict__ kb, float* __restrict__ vb) {
    const int s = blockIdx.x;
    const int bt = blockIdx.y;
    const int t = bt & (T_ - 1);
    const int b = bt >> 11;
    const int c = (s << 7) + threadIdx.x;
    const size_t base = (size_t)bt * CONV_DIM_ + c;
    const float w0 = cw[c * 4], w1 = cw[c * 4 + 1], w2 = cw[c * 4 + 2], w3 = cw[c * 4 + 3];
    float acc = (float)mixed[base] * w3;
    if (t >= 1) acc += (float)mixed[base - CONV_DIM_] * w2;
    if (t >= 2) acc += (float)mixed[base - 2 * CONV_DIM_] * w1;
    if (t >= 3) acc += (float)mixed[base - 3 * CONV_DIM_] * w0;
    const float val = acc / (1.f + __expf(-acc));  // silu

    __shared__ float red[2];
    if (s < 32) {
        float ss = val * val;
#pragma unroll
        for (int o = 1; o < 64; o <<= 1) ss += __shfl_xor(ss, o);
        if ((threadIdx.x & 63) == 0) red[threadIdx.x >> 6] = ss;
        __syncthreads();
        const float scale = rsqrtf(red[0] + red[1] + 1e-6f);
        const int h = s & 15;
        const size_t oidx = (((size_t)(b * H_ + h)) * T_ + t) * 128 + threadIdx.x;
        if (s < 16) qb[oidx] = val * scale * 0.08838834764831845f;  // * DK^-0.5
        else        kb[oidx] = val * scale;
    } else {
        const int h = s - 32;
        const size_t oidx = (((size_t)(b * H_ + h)) * T_ + t) * 128 + threadIdx.x;
        vb[oidx] = val;
    }
}

// ---------------- beta = sigmoid(X@Wb), g = -exp(A_log)*softplus(X@Wa + dt_bias) ----------------
__global__ void gbeta_kernel(const float* __restrict__ X, const float* __restrict__ Wb,
                             const float* __restrict__ Wa, const float* __restrict__ dtb,
                             const float* __restrict__ Alog,
                             float* __restrict__ gbuf, float* __restrict__ bbuf) {
    const int bt = blockIdx.x;
    const int tid = threadIdx.x;
    if (tid >= 32) return;
    const int h = tid & 15;
    const float* W = (tid < 16) ? Wb : Wa;
    const float* x = X + (size_t)bt * D_;
    float s = 0.f;
    for (int j = 0; j < D_; j += 4) {
        float4 xv = *(const float4*)(x + j);
        s += xv.x * W[(j + 0) * H_ + h] + xv.y * W[(j + 1) * H_ + h] +
             xv.z * W[(j + 2) * H_ + h] + xv.w * W[(j + 3) * H_ + h];
    }
    const int t = bt & (T_ - 1), b = bt >> 11;
    const size_t o = ((size_t)(b * H_ + h)) * T_ + t;
    if (tid < 16) {
        bbuf[o] = 1.f / (1.f + __expf(-s));
    } else {
        const float xx = s + dtb[h];
        const float sp = (xx > 15.f) ? xx : log1pf(__expf(xx));
        gbuf[o] = -__expf(Alog[h]) * sp;
    }
}

// ---------------- gated delta rule scan ----------------
// 128 blocks = (b,h) x 4 column-quarters; 256 thr = 4 waves; wave owns 8 cols;
// lane: col = quarter*32 + wave*8 + (lane>>3), rows = (lane&7)*16..+15. No barriers.
__global__ __launch_bounds__(256) void scan_kernel(
    const float* __restrict__ qb, const float* __restrict__ kb, const float* __restrict__ vb,
    const float* __restrict__ gb, const float* __restrict__ bb, float* __restrict__ ob) {
    const int blk = blockIdx.x;
    const int bh = blk >> 2;
    const int quarter = blk & 3;
    const int tid = threadIdx.x;
    const int wave = tid >> 6, lane = tid & 63;
    const int col = (quarter << 5) + (wave << 3) + (lane >> 3);
    const int rowblk = lane & 7;
    const size_t base = (size_t)bh * T_ * 128;
    const float* kp = kb + base + (rowblk << 4);
    const float* qp = qb + base + (rowblk << 4);
    const float* vp = vb + base + col;
    const float* gp = gb + (size_t)bh * T_;
    const float* bp = bb + (size_t)bh * T_;
    float* op = ob + base + col;

    float S[16];
#pragma unroll
    for (int i = 0; i < 16; ++i) S[i] = 0.f;

    float4 kc[4], qc[4];
#pragma unroll
    for (int i = 0; i < 4; ++i) {
        kc[i] = *(const float4*)(kp + (i << 2));
        qc[i] = *(const float4*)(qp + (i << 2));
    }
    float vc = *vp, gc = gp[0], bc = bp[0];

    for (int t = 0; t < T_; ++t) {
        const int tn = (t + 1 < T_) ? (t + 1) : t;  // clamped prefetch
        float4 kn[4], qn[4];
#pragma unroll
        for (int i = 0; i < 4; ++i) {
            kn[i] = *(const float4*)(kp + (size_t)tn * 128 + (i << 2));
            qn[i] = *(const float4*)(qp + (size_t)tn * 128 + (i << 2));
        }
        const float vn = vp[(size_t)tn * 128], gn = gp[tn], bn = bp[tn];

        const float eg = __expf(gc);
        float kv = 0.f;
#pragma unroll
        for (int i = 0; i < 4; ++i) {
            S[4*i+0] *= eg; kv += kc[i].x * S[4*i+0];
            S[4*i+1] *= eg; kv += kc[i].y * S[4*i+1];
            S[4*i+2] *= eg; kv += kc[i].z * S[4*i+2];
            S[4*i+3] *= eg; kv += kc[i].w * S[4*i+3];
        }
        kv += __shfl_xor(kv, 1); kv += __shfl_xor(kv, 2); kv += __shfl_xor(kv, 4);
        const float delta = (vc - kv) * bc;
        float o = 0.f;
#pragma unroll
        for (int i = 0; i < 4; ++i) {
            S[4*i+0] += kc[i].x * delta; o += qc[i].x * S[4*i+0];
            S[4*i+1] += kc[i].y * delta; o += qc[i].y * S[4*i+1];
            S[4*i+2] += kc[i].z * delta; o += qc[i].z * S[4*i+2];
            S[4*i+3] += kc[i].w * delta; o += qc[i].w * S[4*i+3];
        }
        o += __shfl_xor(o, 1); o += __shfl_xor(o, 2); o += __shfl_xor(o, 4);
        if (rowblk == 0) op[(size_t)t * 128] = o;
#pragma unroll
        for (int i = 0; i < 4; ++i) { kc[i] = kn[i]; qc[i] = qn[i]; }
        vc = vn; gc = gn; bc = bn;
    }
}

// ---------------- o = o*silu(z); RMSNorm over DV; -> bf16 [B*T, 2048] ----------------
__global__ void gated_norm_kernel(const float* __restrict__ ob, const bf16* __restrict__ z,
                                  const float* __restrict__ nw, bf16* __restrict__ onorm) {
    const int idx = blockIdx.x;  // B*T*H
    const int h = idx & (H_ - 1);
    const int bt = idx >> 4;
    const int t = bt & (T_ - 1);
    const int b = bt >> 11;
    const int tid = threadIdx.x;  // 64
    const size_t obase = (((size_t)(b * H_ + h)) * T_ + t) * 128;
    const size_t zbase = (size_t)bt * 2048 + (h << 7);
    float o1 = ob[obase + tid], o2 = ob[obase + tid + 64];
    const float z1 = (float)z[zbase + tid], z2 = (float)z[zbase + tid + 64];
    o1 *= z1 / (1.f + __expf(-z1));
    o2 *= z2 / (1.f + __expf(-z2));
    float ss = o1 * o1 + o2 * o2;
#pragma unroll
    for (int o = 1; o < 64; o <<= 1) ss += __shfl_xor(ss, o);
    const float scale = rsqrtf(ss * (1.f / 128.f) + 1e-6f);
    onorm[zbase + tid]      = (bf16)(o1 * scale * nw[tid]);
    onorm[zbase + tid + 64] = (bf16)(o2 * scale * nw[tid + 64]);
}

extern "C" void kernel_launch(void* const* d_in, const int* in_sizes, int n_in,
                              void* d_out, int out_size, void* d_ws, size_t ws_size,
                              hipStream_t stream) {
    const float* X    = (const float*)d_in[0];
    const float* Wqkv = (const float*)d_in[1];
    const float* cw   = (const float*)d_in[2];
    const float* Wz   = (const float*)d_in[3];
    const float* Wb   = (const float*)d_in[4];
    const float* Wa   = (const float*)d_in[5];
    const float* dtb  = (const float*)d_in[6];
    const float* Alog = (const float*)d_in[7];
    const float* nw   = (const float*)d_in[8];
    const float* Wout = (const float*)d_in[9];
    float* out = (float*)d_out;  // reference output dtype is float32

    // ---- workspace layout (232.5 MB peak, with lifetime-safe aliasing) ----
    char* ws = (char*)d_ws;
    size_t off = 0;
    auto alloc = [&](size_t bytes) -> char* {
        char* p = ws + off;
        off += (bytes + 255) & ~(size_t)255;
        return p;
    };
    bf16*  Xb     = (bf16*)alloc((size_t)B_ * T_ * D_ * 2);          // 16 MB [dead after GEMM2 -> onorm]
    char*  wqkvt_p = alloc((size_t)CONV_DIM_ * D_ * 2);              // 24 MB [dead after GEMM1]
    char*  wzt_p   = alloc((size_t)D_ * D_ * 2);                     //  8 MB [dead after GEMM2]
    bf16*  Wqkvt  = (bf16*)wqkvt_p;
    bf16*  Wzt    = (bf16*)wzt_p;
    bf16*  Woutt  = (bf16*)alloc((size_t)D_ * D_ * 2);               //  8 MB [live to end]
    bf16*  mixedb = (bf16*)alloc((size_t)B_ * T_ * CONV_DIM_ * 2);   // 96 MB [dead after conv -> obuf]
    bf16*  zb     = (bf16*)alloc((size_t)B_ * T_ * D_ * 2);          // 16 MB
    float* kbuf   = (float*)alloc((size_t)B_ * T_ * D_ * 4);         // 32 MB
    float* vbuf   = (float*)alloc((size_t)B_ * T_ * D_ * 4);         // 32 MB
    float* gbuf   = (float*)alloc((size_t)B_ * T_ * H_ * 4);         // 256 KB
    float* bbuf   = (float*)alloc((size_t)B_ * T_ * H_ * 4);         // 256 KB
    // aliases (written strictly after previous tenant's last read):
    float* qbuf   = (float*)wqkvt_p;   // 32 MB spans Wqkvt+Wzt (dead after GEMM2; conv writes later)
    float* obuf   = (float*)mixedb;    // 32 MB of the 96 MB mixed region (dead after conv)
    bf16*  onorm  = (bf16*)Xb;         // 16 MB (Xb dead after GEMM2)

    cvt_bf16_kernel<<<dim3((B_ * T_ * D_ / 4 + 255) / 256), dim3(256), 0, stream>>>(X, Xb, B_ * T_ * D_ / 4);
    transpose_kernel<<<dim3(CONV_DIM_ / 32, D_ / 32), dim3(256), 0, stream>>>(Wqkv, Wqkvt, D_, CONV_DIM_);
    transpose_kernel<<<dim3(D_ / 32, D_ / 32), dim3(256), 0, stream>>>(Wz, Wzt, D_, D_);
    transpose_kernel<<<dim3(D_ / 32, D_ / 32), dim3(256), 0, stream>>>(Wout, Woutt, D_, D_);

    gemm_kernel<bf16><<<dim3(CONV_DIM_ / 128, B_ * T_ / 128), dim3(256), 0, stream>>>(
        Xb, Wqkvt, mixedb, B_ * T_, CONV_DIM_, D_);
    gemm_kernel<bf16><<<dim3(D_ / 128, B_ * T_ / 128), dim3(256), 0, stream>>>(
        Xb, Wzt, zb, B_ * T_, D_, D_);

    gbeta_kernel<<<dim3(B_ * T_), dim3(64), 0, stream>>>(X, Wb, Wa, dtb, Alog, gbuf, bbuf);
    conv_silu_kernel<<<dim3(CONV_DIM_ / 128, B_ * T_), dim3(128), 0, stream>>>(mixedb, cw, qbuf, kbuf, vbuf);
    scan_kernel<<<dim3(128), dim3(256), 0, stream>>>(qbuf, kbuf, vbuf, gbuf, bbuf, obuf);
    gated_norm_kernel<<<dim3(B_ * T_ * H_), dim3(64), 0, stream>>>(obuf, zb, nw, onorm);

    gemm_kernel<float><<<dim3(D_ / 128, B_ * T_ / 128), dim3(256), 0, stream>>>(
        onorm, Woutt, out, B_ * T_, D_, D_);
}

// Round 3
// 2107.175 us; speedup vs baseline: 1.1063x; 1.1063x over previous
//
#include <hip/hip_runtime.h>

#define B_ 2
#define T_ 2048
#define D_ 2048
#define H_ 16
#define CONV_DIM_ 6144

typedef __bf16 bf16;
typedef bf16 bf16x8 __attribute__((ext_vector_type(8)));
typedef bf16 bf16x4 __attribute__((ext_vector_type(4)));
typedef float floatx4 __attribute__((ext_vector_type(4)));

// ---------------- elementwise f32 -> bf16 ----------------
__global__ void cvt_bf16_kernel(const float* __restrict__ in, bf16* __restrict__ out, int n4) {
    int i = blockIdx.x * 256 + threadIdx.x;
    if (i < n4) {
        float4 v = ((const float4*)in)[i];
        bf16x4 o = { (bf16)v.x, (bf16)v.y, (bf16)v.z, (bf16)v.w };
        *(bf16x4*)(out + 4 * (size_t)i) = o;
    }
}

// ---------------- transpose f32 [R,Cn] -> bf16 [Cn,R] ----------------
__global__ void transpose_kernel(const float* __restrict__ in, bf16* __restrict__ out, int R, int Cn) {
    __shared__ float tile[32][33];
    const int c0 = blockIdx.x << 5, r0 = blockIdx.y << 5;
    const int tx = threadIdx.x & 31, ty = threadIdx.x >> 5;
#pragma unroll
    for (int i = 0; i < 4; ++i) {
        int r = ty + (i << 3);
        tile[r][tx] = in[(size_t)(r0 + r) * Cn + c0 + tx];
    }
    __syncthreads();
#pragma unroll
    for (int i = 0; i < 4; ++i) {
        int cc = ty + (i << 3);
        out[(size_t)(c0 + cc) * R + r0 + tx] = (bf16)tile[tx][cc];
    }
}

// ---------------- bf16 MFMA GEMM: A[M,K] x Bt[N,K] -> C[M,N] ----------------
// 128x128 block tile, 4 waves (2x2 of 64x64), BK=64, XOR-swizzled LDS.
template <typename OutT>
__global__ __launch_bounds__(256) void gemm_kernel(
    const bf16* __restrict__ A, const bf16* __restrict__ Bt, OutT* __restrict__ C,
    int M, int N, int K) {
    __shared__ bf16 As[128 * 64];
    __shared__ bf16 Bs[128 * 64];
    const int tid = threadIdx.x;
    const int m0 = blockIdx.y << 7;
    const int n0 = blockIdx.x << 7;
    const int wave = tid >> 6, lane = tid & 63;
    const int wm = (wave >> 1) << 6, wn = (wave & 1) << 6;
    const int lrow = lane & 15, quad = lane >> 4;

    floatx4 acc[4][4];
#pragma unroll
    for (int mt = 0; mt < 4; ++mt)
#pragma unroll
        for (int nt = 0; nt < 4; ++nt)
            acc[mt][nt] = floatx4{0.f, 0.f, 0.f, 0.f};

    for (int k0 = 0; k0 < K; k0 += 64) {
        __syncthreads();
#pragma unroll
        for (int i = 0; i < 4; ++i) {
            int idx = (i << 8) + tid;
            int r = idx >> 3, c8 = idx & 7;
            int u = c8 ^ (r & 7);  // XOR swizzle on 16B units
            *(uint4*)(&As[(r << 6) + (u << 3)]) = *(const uint4*)(A + (size_t)(m0 + r) * K + k0 + (c8 << 3));
            *(uint4*)(&Bs[(r << 6) + (u << 3)]) = *(const uint4*)(Bt + (size_t)(n0 + r) * K + k0 + (c8 << 3));
        }
        __syncthreads();
#pragma unroll
        for (int kk = 0; kk < 64; kk += 32) {
            const int sw = (((kk >> 3) + quad) ^ (lrow & 7)) << 3;
            bf16x8 af[4], bfr[4];
#pragma unroll
            for (int mt = 0; mt < 4; ++mt) {
                af[mt]  = *(const bf16x8*)(&As[((wm + (mt << 4) + lrow) << 6) + sw]);
                bfr[mt] = *(const bf16x8*)(&Bs[((wn + (mt << 4) + lrow) << 6) + sw]);
            }
#pragma unroll
            for (int mt = 0; mt < 4; ++mt)
#pragma unroll
                for (int nt = 0; nt < 4; ++nt)
                    acc[mt][nt] = __builtin_amdgcn_mfma_f32_16x16x32_bf16(af[mt], bfr[nt], acc[mt][nt], 0, 0, 0);
        }
    }
    // C/D layout: col = lane&15, row = quad*4 + i  (m89/m91-verified)
#pragma unroll
    for (int mt = 0; mt < 4; ++mt)
#pragma unroll
        for (int nt = 0; nt < 4; ++nt) {
            const int col = n0 + wn + (nt << 4) + lrow;
            const int rowb = m0 + wm + (mt << 4) + (quad << 2);
#pragma unroll
            for (int i2 = 0; i2 < 4; ++i2)
                C[(size_t)(rowb + i2) * N + col] = (OutT)acc[mt][nt][i2];
        }
}

// ---------------- depthwise causal conv (K=4) + silu + split + l2norm ----------------
// grid (48, B*T), block 128. slices: 0-15 q(heads), 16-31 k, 32-47 v
__global__ void conv_silu_kernel(const bf16* __restrict__ mixed, const float* __restrict__ cw,
                                 float* __restrict__ qb, float* __restrict__ kb, float* __restrict__ vb) {
    const int s = blockIdx.x;
    const int bt = blockIdx.y;
    const int t = bt & (T_ - 1);
    const int b = bt >> 11;
    const int c = (s << 7) + threadIdx.x;
    const size_t base = (size_t)bt * CONV_DIM_ + c;
    const float w0 = cw[c * 4], w1 = cw[c * 4 + 1], w2 = cw[c * 4 + 2], w3 = cw[c * 4 + 3];
    float acc = (float)mixed[base] * w3;
    if (t >= 1) acc += (float)mixed[base - CONV_DIM_] * w2;
    if (t >= 2) acc += (float)mixed[base - 2 * CONV_DIM_] * w1;
    if (t >= 3) acc += (float)mixed[base - 3 * CONV_DIM_] * w0;
    const float val = acc / (1.f + __expf(-acc));  // silu

    __shared__ float red[2];
    if (s < 32) {
        float ss = val * val;
#pragma unroll
        for (int o = 1; o < 64; o <<= 1) ss += __shfl_xor(ss, o);
        if ((threadIdx.x & 63) == 0) red[threadIdx.x >> 6] = ss;
        __syncthreads();
        const float scale = rsqrtf(red[0] + red[1] + 1e-6f);
        const int h = s & 15;
        const size_t oidx = (((size_t)(b * H_ + h)) * T_ + t) * 128 + threadIdx.x;
        if (s < 16) qb[oidx] = val * scale * 0.08838834764831845f;  // * DK^-0.5
        else        kb[oidx] = val * scale;
    } else {
        const int h = s - 32;
        const size_t oidx = (((size_t)(b * H_ + h)) * T_ + t) * 128 + threadIdx.x;
        vb[oidx] = val;
    }
}

// ---------------- beta = sigmoid(X@Wb), g = -exp(A_log)*softplus(X@Wa + dt_bias) ----------------
__global__ void gbeta_kernel(const float* __restrict__ X, const float* __restrict__ Wb,
                             const float* __restrict__ Wa, const float* __restrict__ dtb,
                             const float* __restrict__ Alog,
                             float* __restrict__ gbuf, float* __restrict__ bbuf) {
    const int bt = blockIdx.x;
    const int tid = threadIdx.x;
    if (tid >= 32) return;
    const int h = tid & 15;
    const float* W = (tid < 16) ? Wb : Wa;
    const float* x = X + (size_t)bt * D_;
    float s = 0.f;
    for (int j = 0; j < D_; j += 4) {
        float4 xv = *(const float4*)(x + j);
        s += xv.x * W[(j + 0) * H_ + h] + xv.y * W[(j + 1) * H_ + h] +
             xv.z * W[(j + 2) * H_ + h] + xv.w * W[(j + 3) * H_ + h];
    }
    const int t = bt & (T_ - 1), b = bt >> 11;
    const size_t o = ((size_t)(b * H_ + h)) * T_ + t;
    if (tid < 16) {
        bbuf[o] = 1.f / (1.f + __expf(-s));
    } else {
        const float xx = s + dtb[h];
        const float sp = (xx > 15.f) ? xx : log1pf(__expf(xx));
        gbuf[o] = -__expf(Alog[h]) * sp;
    }
}

// ---------------- gated delta rule scan ----------------
// 512 blocks = (b,h) x 16 column-groups of 8 cols; 256 thr = 4 waves.
// Wave owns 2 cols (32 lanes each); lane: col = grp*8 + wave*2 + (lane>>5),
// rows = (lane&31)*4 .. +3. Reductions = 5 shfl_xor within 32-lane halves.
// 2-deep register prefetch ring. No barriers, no LDS.
__global__ __launch_bounds__(256) void scan_kernel(
    const float* __restrict__ qb, const float* __restrict__ kb, const float* __restrict__ vb,
    const float* __restrict__ gb, const float* __restrict__ bb, float* __restrict__ ob) {
    const int blk = blockIdx.x;
    const int bh = blk >> 4;
    const int grp = blk & 15;
    const int tid = threadIdx.x;
    const int wave = tid >> 6, lane = tid & 63;
    const int col = (grp << 3) + (wave << 1) + (lane >> 5);
    const int rowblk = lane & 31;
    const size_t base = (size_t)bh * T_ * 128;
    const float* kp = kb + base + (rowblk << 2);
    const float* qp = qb + base + (rowblk << 2);
    const float* vp = vb + base + col;
    const float* gp = gb + (size_t)bh * T_;
    const float* bp = bb + (size_t)bh * T_;
    float* op = ob + base + col;

    float S0 = 0.f, S1 = 0.f, S2 = 0.f, S3 = 0.f;

    float4 kr[2], qr[2];
    float vr[2], gr[2], br[2];
#pragma unroll
    for (int i = 0; i < 2; ++i) {
        kr[i] = *(const float4*)(kp + (size_t)i * 128);
        qr[i] = *(const float4*)(qp + (size_t)i * 128);
        vr[i] = vp[(size_t)i * 128];
        gr[i] = gp[i];
        br[i] = bp[i];
    }

    for (int t = 0; t < T_; ++t) {
        const int cur = t & 1;
        const float4 kc = kr[cur], qc = qr[cur];
        const float vc = vr[cur], gc = gr[cur], bc = br[cur];

        // refill ring slot for t+2 (clamped; surplus values never used)
        const int tp = (t + 2 < T_) ? t + 2 : t;
        kr[cur] = *(const float4*)(kp + (size_t)tp * 128);
        qr[cur] = *(const float4*)(qp + (size_t)tp * 128);
        vr[cur] = vp[(size_t)tp * 128];
        gr[cur] = gp[tp];
        br[cur] = bp[tp];

        const float eg = __expf(gc);
        S0 *= eg; S1 *= eg; S2 *= eg; S3 *= eg;
        float kv = kc.x * S0 + kc.y * S1 + kc.z * S2 + kc.w * S3;
        kv += __shfl_xor(kv, 1); kv += __shfl_xor(kv, 2); kv += __shfl_xor(kv, 4);
        kv += __shfl_xor(kv, 8); kv += __shfl_xor(kv, 16);
        const float delta = (vc - kv) * bc;
        S0 += kc.x * delta; S1 += kc.y * delta; S2 += kc.z * delta; S3 += kc.w * delta;
        float o = qc.x * S0 + qc.y * S1 + qc.z * S2 + qc.w * S3;
        o += __shfl_xor(o, 1); o += __shfl_xor(o, 2); o += __shfl_xor(o, 4);
        o += __shfl_xor(o, 8); o += __shfl_xor(o, 16);
        if (rowblk == 0) op[(size_t)t * 128] = o;
    }
}

// ---------------- o = o*silu(z); RMSNorm over DV; -> bf16 [B*T, 2048] ----------------
__global__ void gated_norm_kernel(const float* __restrict__ ob, const bf16* __restrict__ z,
                                  const float* __restrict__ nw, bf16* __restrict__ onorm) {
    const int idx = blockIdx.x;  // B*T*H
    const int h = idx & (H_ - 1);
    const int bt = idx >> 4;
    const int t = bt & (T_ - 1);
    const int b = bt >> 11;
    const int tid = threadIdx.x;  // 64
    const size_t obase = (((size_t)(b * H_ + h)) * T_ + t) * 128;
    const size_t zbase = (size_t)bt * 2048 + (h << 7);
    float o1 = ob[obase + tid], o2 = ob[obase + tid + 64];
    const float z1 = (float)z[zbase + tid], z2 = (float)z[zbase + tid + 64];
    o1 *= z1 / (1.f + __expf(-z1));
    o2 *= z2 / (1.f + __expf(-z2));
    float ss = o1 * o1 + o2 * o2;
#pragma unroll
    for (int o = 1; o < 64; o <<= 1) ss += __shfl_xor(ss, o);
    const float scale = rsqrtf(ss * (1.f / 128.f) + 1e-6f);
    onorm[zbase + tid]      = (bf16)(o1 * scale * nw[tid]);
    onorm[zbase + tid + 64] = (bf16)(o2 * scale * nw[tid + 64]);
}

extern "C" void kernel_launch(void* const* d_in, const int* in_sizes, int n_in,
                              void* d_out, int out_size, void* d_ws, size_t ws_size,
                              hipStream_t stream) {
    const float* X    = (const float*)d_in[0];
    const float* Wqkv = (const float*)d_in[1];
    const float* cw   = (const float*)d_in[2];
    const float* Wz   = (const float*)d_in[3];
    const float* Wb   = (const float*)d_in[4];
    const float* Wa   = (const float*)d_in[5];
    const float* dtb  = (const float*)d_in[6];
    const float* Alog = (const float*)d_in[7];
    const float* nw   = (const float*)d_in[8];
    const float* Wout = (const float*)d_in[9];
    float* out = (float*)d_out;  // reference output dtype is float32

    // ---- workspace layout (232.5 MB peak, with lifetime-safe aliasing) ----
    char* ws = (char*)d_ws;
    size_t off = 0;
    auto alloc = [&](size_t bytes) -> char* {
        char* p = ws + off;
        off += (bytes + 255) & ~(size_t)255;
        return p;
    };
    bf16*  Xb     = (bf16*)alloc((size_t)B_ * T_ * D_ * 2);          // 16 MB [dead after GEMM2 -> onorm]
    char*  wqkvt_p = alloc((size_t)CONV_DIM_ * D_ * 2);              // 24 MB [dead after GEMM1]
    char*  wzt_p   = alloc((size_t)D_ * D_ * 2);                     //  8 MB [dead after GEMM2]
    bf16*  Wqkvt  = (bf16*)wqkvt_p;
    bf16*  Wzt    = (bf16*)wzt_p;
    bf16*  Woutt  = (bf16*)alloc((size_t)D_ * D_ * 2);               //  8 MB [live to end]
    bf16*  mixedb = (bf16*)alloc((size_t)B_ * T_ * CONV_DIM_ * 2);   // 96 MB [dead after conv -> obuf]
    bf16*  zb     = (bf16*)alloc((size_t)B_ * T_ * D_ * 2);          // 16 MB
    float* kbuf   = (float*)alloc((size_t)B_ * T_ * D_ * 4);         // 32 MB
    float* vbuf   = (float*)alloc((size_t)B_ * T_ * D_ * 4);         // 32 MB
    float* gbuf   = (float*)alloc((size_t)B_ * T_ * H_ * 4);         // 256 KB
    float* bbuf   = (float*)alloc((size_t)B_ * T_ * H_ * 4);         // 256 KB
    // aliases (written strictly after previous tenant's last read):
    float* qbuf   = (float*)wqkvt_p;   // 32 MB spans Wqkvt+Wzt (dead after GEMM2; conv writes later)
    float* obuf   = (float*)mixedb;    // 32 MB of the 96 MB mixed region (dead after conv)
    bf16*  onorm  = (bf16*)Xb;         // 16 MB (Xb dead after GEMM2)

    cvt_bf16_kernel<<<dim3((B_ * T_ * D_ / 4 + 255) / 256), dim3(256), 0, stream>>>(X, Xb, B_ * T_ * D_ / 4);
    transpose_kernel<<<dim3(CONV_DIM_ / 32, D_ / 32), dim3(256), 0, stream>>>(Wqkv, Wqkvt, D_, CONV_DIM_);
    transpose_kernel<<<dim3(D_ / 32, D_ / 32), dim3(256), 0, stream>>>(Wz, Wzt, D_, D_);
    transpose_kernel<<<dim3(D_ / 32, D_ / 32), dim3(256), 0, stream>>>(Wout, Woutt, D_, D_);

    gemm_kernel<bf16><<<dim3(CONV_DIM_ / 128, B_ * T_ / 128), dim3(256), 0, stream>>>(
        Xb, Wqkvt, mixedb, B_ * T_, CONV_DIM_, D_);
    gemm_kernel<bf16><<<dim3(D_ / 128, B_ * T_ / 128), dim3(256), 0, stream>>>(
        Xb, Wzt, zb, B_ * T_, D_, D_);

    gbeta_kernel<<<dim3(B_ * T_), dim3(64), 0, stream>>>(X, Wb, Wa, dtb, Alog, gbuf, bbuf);
    conv_silu_kernel<<<dim3(CONV_DIM_ / 128, B_ * T_), dim3(128), 0, stream>>>(mixedb, cw, qbuf, kbuf, vbuf);
    scan_kernel<<<dim3(512), dim3(256), 0, stream>>>(qbuf, kbuf, vbuf, gbuf, bbuf, obuf);
    gated_norm_kernel<<<dim3(B_ * T_ * H_), dim3(64), 0, stream>>>(obuf, zb, nw, onorm);

    gemm_kernel<float><<<dim3(D_ / 128, B_ * T_ / 128), dim3(256), 0, stream>>>(
        onorm, Woutt, out, B_ * T_, D_, D_);
}

// Round 4
// 769.125 us; speedup vs baseline: 3.0310x; 2.7397x over previous
//
#include <hip/hip_runtime.h>

#define B_ 2
#define T_ 2048
#define D_ 2048
#define H_ 16
#define CONV_DIM_ 6144
#define NC_ 32   // chunks per sequence
#define CK_ 64   // chunk length

typedef __bf16 bf16;
typedef bf16 bf16x8 __attribute__((ext_vector_type(8)));
typedef bf16 bf16x4 __attribute__((ext_vector_type(4)));
typedef float floatx4 __attribute__((ext_vector_type(4)));

// ---------------- elementwise f32 -> bf16 ----------------
__global__ void cvt_bf16_kernel(const float* __restrict__ in, bf16* __restrict__ out, int n4) {
    int i = blockIdx.x * 256 + threadIdx.x;
    if (i < n4) {
        float4 v = ((const float4*)in)[i];
        bf16x4 o = { (bf16)v.x, (bf16)v.y, (bf16)v.z, (bf16)v.w };
        *(bf16x4*)(out + 4 * (size_t)i) = o;
    }
}

// ---------------- transpose f32 [R,Cn] -> bf16 [Cn,R] ----------------
__global__ void transpose_kernel(const float* __restrict__ in, bf16* __restrict__ out, int R, int Cn) {
    __shared__ float tile[32][33];
    const int c0 = blockIdx.x << 5, r0 = blockIdx.y << 5;
    const int tx = threadIdx.x & 31, ty = threadIdx.x >> 5;
#pragma unroll
    for (int i = 0; i < 4; ++i) {
        int r = ty + (i << 3);
        tile[r][tx] = in[(size_t)(r0 + r) * Cn + c0 + tx];
    }
    __syncthreads();
#pragma unroll
    for (int i = 0; i < 4; ++i) {
        int cc = ty + (i << 3);
        out[(size_t)(c0 + cc) * R + r0 + tx] = (bf16)tile[tx][cc];
    }
}

// ---------------- bf16 MFMA GEMM: A[M,K] x Bt[N,K] -> C[M,N] ----------------
template <typename OutT>
__global__ __launch_bounds__(256) void gemm_kernel(
    const bf16* __restrict__ A, const bf16* __restrict__ Bt, OutT* __restrict__ C,
    int M, int N, int K) {
    __shared__ bf16 As[128 * 64];
    __shared__ bf16 Bs[128 * 64];
    const int tid = threadIdx.x;
    const int m0 = blockIdx.y << 7;
    const int n0 = blockIdx.x << 7;
    const int wave = tid >> 6, lane = tid & 63;
    const int wm = (wave >> 1) << 6, wn = (wave & 1) << 6;
    const int lrow = lane & 15, quad = lane >> 4;

    floatx4 acc[4][4];
#pragma unroll
    for (int mt = 0; mt < 4; ++mt)
#pragma unroll
        for (int nt = 0; nt < 4; ++nt)
            acc[mt][nt] = floatx4{0.f, 0.f, 0.f, 0.f};

    for (int k0 = 0; k0 < K; k0 += 64) {
        __syncthreads();
#pragma unroll
        for (int i = 0; i < 4; ++i) {
            int idx = (i << 8) + tid;
            int r = idx >> 3, c8 = idx & 7;
            int u = c8 ^ (r & 7);
            *(uint4*)(&As[(r << 6) + (u << 3)]) = *(const uint4*)(A + (size_t)(m0 + r) * K + k0 + (c8 << 3));
            *(uint4*)(&Bs[(r << 6) + (u << 3)]) = *(const uint4*)(Bt + (size_t)(n0 + r) * K + k0 + (c8 << 3));
        }
        __syncthreads();
#pragma unroll
        for (int kk = 0; kk < 64; kk += 32) {
            const int sw = (((kk >> 3) + quad) ^ (lrow & 7)) << 3;
            bf16x8 af[4], bfr[4];
#pragma unroll
            for (int mt = 0; mt < 4; ++mt) {
                af[mt]  = *(const bf16x8*)(&As[((wm + (mt << 4) + lrow) << 6) + sw]);
                bfr[mt] = *(const bf16x8*)(&Bs[((wn + (mt << 4) + lrow) << 6) + sw]);
            }
#pragma unroll
            for (int mt = 0; mt < 4; ++mt)
#pragma unroll
                for (int nt = 0; nt < 4; ++nt)
                    acc[mt][nt] = __builtin_amdgcn_mfma_f32_16x16x32_bf16(af[mt], bfr[nt], acc[mt][nt], 0, 0, 0);
        }
    }
#pragma unroll
    for (int mt = 0; mt < 4; ++mt)
#pragma unroll
        for (int nt = 0; nt < 4; ++nt) {
            const int col = n0 + wn + (nt << 4) + lrow;
            const int rowb = m0 + wm + (mt << 4) + (quad << 2);
#pragma unroll
            for (int i2 = 0; i2 < 4; ++i2)
                C[(size_t)(rowb + i2) * N + col] = (OutT)acc[mt][nt][i2];
        }
}

// ---------------- depthwise causal conv (K=4) + silu + split + l2norm -> bf16 ----------------
__global__ void conv_silu_kernel(const bf16* __restrict__ mixed, const float* __restrict__ cw,
                                 bf16* __restrict__ qb, bf16* __restrict__ kb, bf16* __restrict__ vb) {
    const int s = blockIdx.x;
    const int bt = blockIdx.y;
    const int t = bt & (T_ - 1);
    const int b = bt >> 11;
    const int c = (s << 7) + threadIdx.x;
    const size_t base = (size_t)bt * CONV_DIM_ + c;
    const float w0 = cw[c * 4], w1 = cw[c * 4 + 1], w2 = cw[c * 4 + 2], w3 = cw[c * 4 + 3];
    float acc = (float)mixed[base] * w3;
    if (t >= 1) acc += (float)mixed[base - CONV_DIM_] * w2;
    if (t >= 2) acc += (float)mixed[base - 2 * CONV_DIM_] * w1;
    if (t >= 3) acc += (float)mixed[base - 3 * CONV_DIM_] * w0;
    const float val = acc / (1.f + __expf(-acc));  // silu

    __shared__ float red[2];
    if (s < 32) {
        float ss = val * val;
#pragma unroll
        for (int o = 1; o < 64; o <<= 1) ss += __shfl_xor(ss, o);
        if ((threadIdx.x & 63) == 0) red[threadIdx.x >> 6] = ss;
        __syncthreads();
        const float scale = rsqrtf(red[0] + red[1] + 1e-6f);
        const int h = s & 15;
        const size_t oidx = (((size_t)(b * H_ + h)) * T_ + t) * 128 + threadIdx.x;
        if (s < 16) qb[oidx] = (bf16)(val * scale * 0.08838834764831845f);
        else        kb[oidx] = (bf16)(val * scale);
    } else {
        const int h = s - 32;
        const size_t oidx = (((size_t)(b * H_ + h)) * T_ + t) * 128 + threadIdx.x;
        vb[oidx] = (bf16)val;
    }
}

// ---------------- beta/g projections ----------------
__global__ void gbeta_kernel(const float* __restrict__ X, const float* __restrict__ Wb,
                             const float* __restrict__ Wa, const float* __restrict__ dtb,
                             const float* __restrict__ Alog,
                             float* __restrict__ gbuf, float* __restrict__ bbuf) {
    const int bt = blockIdx.x;
    const int tid = threadIdx.x;
    if (tid >= 32) return;
    const int h = tid & 15;
    const float* W = (tid < 16) ? Wb : Wa;
    const float* x = X + (size_t)bt * D_;
    float s = 0.f;
    for (int j = 0; j < D_; j += 4) {
        float4 xv = *(const float4*)(x + j);
        s += xv.x * W[(j + 0) * H_ + h] + xv.y * W[(j + 1) * H_ + h] +
             xv.z * W[(j + 2) * H_ + h] + xv.w * W[(j + 3) * H_ + h];
    }
    const int t = bt & (T_ - 1), b = bt >> 11;
    const size_t o = ((size_t)(b * H_ + h)) * T_ + t;
    if (tid < 16) {
        bbuf[o] = 1.f / (1.f + __expf(-s));
    } else {
        const float xx = s + dtb[h];
        const float sp = (xx > 15.f) ? xx : log1pf(__expf(xx));
        gbuf[o] = -__expf(Alog[h]) * sp;
    }
}

// ---------------- chunked delta rule: precompute 1 — KK^T and QK^T per (bh,chunk) ----------------
// 1024 blocks, 256 thr. Araw[u][i][j] = k_i.k_j ; Mraw[u][i][j] = q_i.k_j
__global__ __launch_bounds__(256) void qkkt_kernel(const bf16* __restrict__ qb, const bf16* __restrict__ kb,
                                                   float* __restrict__ Araw, float* __restrict__ Mraw) {
    const int u = blockIdx.x;
    const int bh = u >> 5, nc = u & 31;
    const int t0 = nc * CK_;
    const int tid = threadIdx.x, wave = tid >> 6, lane = tid & 63;
    const int qd = lane >> 4, ln = lane & 15;
    __shared__ bf16 Kc[64 * 136], Qc[64 * 136];
    const size_t kbase = ((size_t)bh * T_ + t0) * 128;
#pragma unroll
    for (int it = 0; it < 4; ++it) {
        int idx = it * 256 + tid;
        int row = idx >> 4, c8 = idx & 15;
        *(uint4*)(&Kc[row * 136 + c8 * 8]) = *(const uint4*)(kb + kbase + row * 128 + c8 * 8);
        *(uint4*)(&Qc[row * 136 + c8 * 8]) = *(const uint4*)(qb + kbase + row * 128 + c8 * 8);
    }
    __syncthreads();
#pragma unroll
    for (int nt = 0; nt < 4; ++nt) {
        floatx4 accA = {0.f, 0.f, 0.f, 0.f}, accM = {0.f, 0.f, 0.f, 0.f};
#pragma unroll
        for (int kk = 0; kk < 4; ++kk) {
            bf16x8 bfr = *(const bf16x8*)(&Kc[(nt * 16 + ln) * 136 + kk * 32 + qd * 8]);
            bf16x8 afK = *(const bf16x8*)(&Kc[(wave * 16 + ln) * 136 + kk * 32 + qd * 8]);
            bf16x8 afQ = *(const bf16x8*)(&Qc[(wave * 16 + ln) * 136 + kk * 32 + qd * 8]);
            accA = __builtin_amdgcn_mfma_f32_16x16x32_bf16(afK, bfr, accA, 0, 0, 0);
            accM = __builtin_amdgcn_mfma_f32_16x16x32_bf16(afQ, bfr, accM, 0, 0, 0);
        }
#pragma unroll
        for (int ii = 0; ii < 4; ++ii) {
            int i = wave * 16 + qd * 4 + ii, j = nt * 16 + ln;
            Araw[(size_t)u * 4096 + i * 64 + j] = accA[ii];
            Mraw[(size_t)u * 4096 + i * 64 + j] = accM[ii];
        }
    }
}

// ---------------- precompute 2 — decay vectors, T = (I+A)^{-1}, masked M ----------------
// 1024 blocks, 64 thr (one wave per (bh,chunk)); lane = column index.
__global__ __launch_bounds__(64) void prep_kernel(
    const float* __restrict__ gbuf, const float* __restrict__ bbuf,
    const float* __restrict__ Araw, const float* __restrict__ Mraw,
    float* __restrict__ lamg, float* __restrict__ ratiog,
    bf16* __restrict__ Tg, bf16* __restrict__ Mg) {
    const int u = blockIdx.x, bh = u >> 5, nc = u & 31, t0 = nc * CK_;
    const int lane = threadIdx.x;
    __shared__ float L[64 * 65];
    __shared__ float cv[64], bv[64];
    float g = gbuf[(size_t)bh * T_ + t0 + lane];
    float beta = bbuf[(size_t)bh * T_ + t0 + lane];
    // inclusive scan of g across 64 lanes
    float c = g;
#pragma unroll
    for (int off = 1; off < 64; off <<= 1) {
        float tval = __shfl_up(c, off);
        if (lane >= off) c += tval;
    }
    float c63 = __shfl(c, 63);
    lamg[(size_t)u * 64 + lane] = __expf(c);
    ratiog[(size_t)u * 64 + lane] = __expf(c63 - c);
    cv[lane] = c; bv[lane] = beta;
    __syncthreads();
    // L = I + A ; A_ij = beta_i * exp(c_i - c_j) * (k_i.k_j), strictly lower
    for (int i = 0; i < 64; ++i) {
        float a = Araw[(size_t)u * 4096 + i * 64 + lane];
        L[i * 65 + lane] = (lane < i) ? bv[i] * __expf(cv[i] - c) * a : 0.f;
    }
    __syncthreads();
    // forward substitution: column `lane` of T = L^{-1} (unit diagonal)
    float t[64];
#pragma unroll
    for (int i = 0; i < 64; ++i) t[i] = (i == lane) ? 1.f : 0.f;
#pragma unroll
    for (int j = 0; j < 63; ++j) {
#pragma unroll
        for (int i = j + 1; i < 64; ++i)
            t[i] -= L[i * 65 + j] * t[j];
    }
#pragma unroll
    for (int i = 0; i < 64; ++i)
        Tg[(size_t)u * 4096 + i * 64 + lane] = (bf16)t[i];
    // M_ij = exp(c_i - c_j) * (q_i.k_j), j <= i (incl diag)
    for (int i = 0; i < 64; ++i) {
        float m = Mraw[(size_t)u * 4096 + i * 64 + lane];
        float mij = (lane <= i) ? __expf(cv[i] - c) * m : 0.f;
        Mg[(size_t)u * 4096 + i * 64 + lane] = (bf16)mij;
    }
}

// ---------------- sequential chunk loop: 128 blocks = 32 bh x 4 v-splits (dv=32) ----------------
__global__ __launch_bounds__(256) void seq_kernel(
    const bf16* __restrict__ qb, const bf16* __restrict__ kb, const bf16* __restrict__ vb,
    const bf16* __restrict__ Tg, const bf16* __restrict__ Mg,
    const float* __restrict__ lamg, const float* __restrict__ ratiog,
    const float* __restrict__ bbuf, float* __restrict__ ob) {
    const int bh = blockIdx.x >> 2;
    const int vs = blockIdx.x & 3;
    const int vbase = vs * 32;
    const int tid = threadIdx.x;
    const int wave = tid >> 6, lane = tid & 63;
    const int qd = lane >> 4, ln = lane & 15;

    __shared__ bf16 Kc[64 * 136], Qc[64 * 136], Ktp[128 * 72], Tt[64 * 72], Mm[64 * 72];
    __shared__ bf16 Sbf[32 * 136], bT[32 * 72], Dt[32 * 72];
    __shared__ float Sf[32 * 132];

    // zero state
    for (int idx = tid; idx < 32 * 132; idx += 256) Sf[idx] = 0.f;
    for (int idx = tid; idx < 32 * 136; idx += 256) Sbf[idx] = (bf16)0.f;
    __syncthreads();

    for (int nc = 0; nc < NC_; ++nc) {
        const int u = bh * NC_ + nc;
        const int t0 = nc * CK_;
        const size_t kbase = ((size_t)bh * T_ + t0) * 128;

        // ---- stage P: stage K, Q, K' (transposed+scaled), T, M into LDS ----
#pragma unroll
        for (int it = 0; it < 4; ++it) {
            int idx = it * 256 + tid;
            int row = idx >> 4, c8 = idx & 15;
            uint4 kv4 = *(const uint4*)(kb + kbase + row * 128 + c8 * 8);
            *(uint4*)(&Kc[row * 136 + c8 * 8]) = kv4;
            uint4 qv4 = *(const uint4*)(qb + kbase + row * 128 + c8 * 8);
            *(uint4*)(&Qc[row * 136 + c8 * 8]) = qv4;
            float rr = ratiog[(size_t)u * 64 + row];
            bf16 tmp[8]; *(uint4*)tmp = kv4;
#pragma unroll
            for (int cc = 0; cc < 8; ++cc)
                Ktp[(c8 * 8 + cc) * 72 + row] = (bf16)((float)tmp[cc] * rr);
        }
#pragma unroll
        for (int it = 0; it < 2; ++it) {
            int idx = it * 256 + tid;
            int row = idx >> 3, c8 = idx & 7;
            *(uint4*)(&Tt[row * 72 + c8 * 8]) = *(const uint4*)(Tg + (size_t)u * 4096 + row * 64 + c8 * 8);
            *(uint4*)(&Mm[row * 72 + c8 * 8]) = *(const uint4*)(Mg + (size_t)u * 4096 + row * 64 + c8 * 8);
        }
        __syncthreads();  // B0

        // ---- stage 1: KS = K @ S  (rows i = wave*16.., 2 n-tiles) ----
        floatx4 ks[2];
#pragma unroll
        for (int nt = 0; nt < 2; ++nt) {
            floatx4 acc = {0.f, 0.f, 0.f, 0.f};
#pragma unroll
            for (int kk = 0; kk < 4; ++kk) {
                bf16x8 af = *(const bf16x8*)(&Kc[(wave * 16 + ln) * 136 + kk * 32 + qd * 8]);
                bf16x8 bf = *(const bf16x8*)(&Sbf[(nt * 16 + ln) * 136 + kk * 32 + qd * 8]);
                acc = __builtin_amdgcn_mfma_f32_16x16x32_bf16(af, bf, acc, 0, 0, 0);
            }
            ks[nt] = acc;
        }
        // ---- stage 2: b = beta*(V - lam*KS) -> bT[v][i] (bf16) ----
#pragma unroll
        for (int nt = 0; nt < 2; ++nt) {
            int vloc = nt * 16 + ln;
#pragma unroll
            for (int ii = 0; ii < 4; ++ii) {
                int i = wave * 16 + qd * 4 + ii;
                float lam = lamg[(size_t)u * 64 + i];
                float beta = bbuf[(size_t)bh * T_ + t0 + i];
                float vv = (float)vb[kbase + (size_t)i * 128 + vbase + vloc];
                bT[vloc * 72 + i] = (bf16)(beta * (vv - lam * ks[nt][ii]));
            }
        }
        __syncthreads();  // B1

        // ---- stage 3: D = T @ b ; write Dt[v][i] ----
#pragma unroll
        for (int nt = 0; nt < 2; ++nt) {
            floatx4 acc = {0.f, 0.f, 0.f, 0.f};
#pragma unroll
            for (int kk = 0; kk < 2; ++kk) {
                bf16x8 af = *(const bf16x8*)(&Tt[(wave * 16 + ln) * 72 + kk * 32 + qd * 8]);
                bf16x8 bf = *(const bf16x8*)(&bT[(nt * 16 + ln) * 72 + kk * 32 + qd * 8]);
                acc = __builtin_amdgcn_mfma_f32_16x16x32_bf16(af, bf, acc, 0, 0, 0);
            }
            int vloc = nt * 16 + ln;
            int i0 = wave * 16 + qd * 4;
            bf16x4 dw = { (bf16)acc[0], (bf16)acc[1], (bf16)acc[2], (bf16)acc[3] };
            *(bf16x4*)(&Dt[vloc * 72 + i0]) = dw;
        }
        __syncthreads();  // B2

        // ---- stage 4: O = lam ⊙ (Q@S) + M@D -> global ----
#pragma unroll
        for (int nt = 0; nt < 2; ++nt) {
            floatx4 acc = {0.f, 0.f, 0.f, 0.f};
#pragma unroll
            for (int kk = 0; kk < 4; ++kk) {
                bf16x8 af = *(const bf16x8*)(&Qc[(wave * 16 + ln) * 136 + kk * 32 + qd * 8]);
                bf16x8 bf = *(const bf16x8*)(&Sbf[(nt * 16 + ln) * 136 + kk * 32 + qd * 8]);
                acc = __builtin_amdgcn_mfma_f32_16x16x32_bf16(af, bf, acc, 0, 0, 0);
            }
            floatx4 o;
#pragma unroll
            for (int ii = 0; ii < 4; ++ii) {
                int i = wave * 16 + qd * 4 + ii;
                o[ii] = acc[ii] * lamg[(size_t)u * 64 + i];
            }
#pragma unroll
            for (int kk = 0; kk < 2; ++kk) {
                bf16x8 af = *(const bf16x8*)(&Mm[(wave * 16 + ln) * 72 + kk * 32 + qd * 8]);
                bf16x8 bf = *(const bf16x8*)(&Dt[(nt * 16 + ln) * 72 + kk * 32 + qd * 8]);
                o = __builtin_amdgcn_mfma_f32_16x16x32_bf16(af, bf, o, 0, 0, 0);
            }
            int vglob = vbase + nt * 16 + ln;
#pragma unroll
            for (int ii = 0; ii < 4; ++ii) {
                int i = wave * 16 + qd * 4 + ii;
                ob[kbase + (size_t)i * 128 + vglob] = o[ii];
            }
        }
        // ---- stage 5: S = lam_last*S + K'^T @ D  (RMW Sf) ----
        float lamlast = lamg[(size_t)u * 64 + 63];
#pragma unroll
        for (int mt = 0; mt < 2; ++mt) {
            int kt = wave * 2 + mt;  // m-tile over k-dim (8 tiles)
#pragma unroll
            for (int nt = 0; nt < 2; ++nt) {
                floatx4 acc = {0.f, 0.f, 0.f, 0.f};
#pragma unroll
                for (int kk = 0; kk < 2; ++kk) {
                    bf16x8 af = *(const bf16x8*)(&Ktp[(kt * 16 + ln) * 72 + kk * 32 + qd * 8]);
                    bf16x8 bf = *(const bf16x8*)(&Dt[(nt * 16 + ln) * 72 + kk * 32 + qd * 8]);
                    acc = __builtin_amdgcn_mfma_f32_16x16x32_bf16(af, bf, acc, 0, 0, 0);
                }
                int vloc = nt * 16 + ln;
                int k0 = kt * 16 + qd * 4;
                floatx4 sold = *(floatx4*)(&Sf[vloc * 132 + k0]);
                floatx4 snew;
#pragma unroll
                for (int ii = 0; ii < 4; ++ii) snew[ii] = sold[ii] * lamlast + acc[ii];
                *(floatx4*)(&Sf[vloc * 132 + k0]) = snew;
            }
        }
        __syncthreads();  // B3
        // refresh Sbf from Sf
#pragma unroll
        for (int it = 0; it < 2; ++it) {
            int idx = it * 256 + tid;
            int vloc = idx >> 4, k0 = (idx & 15) * 8;
            floatx4 s0 = *(floatx4*)(&Sf[vloc * 132 + k0]);
            floatx4 s1 = *(floatx4*)(&Sf[vloc * 132 + k0 + 4]);
            bf16x8 sb = { (bf16)s0[0], (bf16)s0[1], (bf16)s0[2], (bf16)s0[3],
                          (bf16)s1[0], (bf16)s1[1], (bf16)s1[2], (bf16)s1[3] };
            *(bf16x8*)(&Sbf[vloc * 136 + k0]) = sb;
        }
        __syncthreads();  // B4
    }
}

// ---------------- o = o*silu(z); RMSNorm over DV; -> bf16 [B*T, 2048] ----------------
__global__ void gated_norm_kernel(const float* __restrict__ ob, const bf16* __restrict__ z,
                                  const float* __restrict__ nw, bf16* __restrict__ onorm) {
    const int idx = blockIdx.x;  // B*T*H
    const int h = idx & (H_ - 1);
    const int bt = idx >> 4;
    const int t = bt & (T_ - 1);
    const int b = bt >> 11;
    const int tid = threadIdx.x;  // 64
    const size_t obase = (((size_t)(b * H_ + h)) * T_ + t) * 128;
    const size_t zbase = (size_t)bt * 2048 + (h << 7);
    float o1 = ob[obase + tid], o2 = ob[obase + tid + 64];
    const float z1 = (float)z[zbase + tid], z2 = (float)z[zbase + tid + 64];
    o1 *= z1 / (1.f + __expf(-z1));
    o2 *= z2 / (1.f + __expf(-z2));
    float ss = o1 * o1 + o2 * o2;
#pragma unroll
    for (int o = 1; o < 64; o <<= 1) ss += __shfl_xor(ss, o);
    const float scale = rsqrtf(ss * (1.f / 128.f) + 1e-6f);
    onorm[zbase + tid]      = (bf16)(o1 * scale * nw[tid]);
    onorm[zbase + tid + 64] = (bf16)(o2 * scale * nw[tid + 64]);
}

extern "C" void kernel_launch(void* const* d_in, const int* in_sizes, int n_in,
                              void* d_out, int out_size, void* d_ws, size_t ws_size,
                              hipStream_t stream) {
    const float* X    = (const float*)d_in[0];
    const float* Wqkv = (const float*)d_in[1];
    const float* cw   = (const float*)d_in[2];
    const float* Wz   = (const float*)d_in[3];
    const float* Wb   = (const float*)d_in[4];
    const float* Wa   = (const float*)d_in[5];
    const float* dtb  = (const float*)d_in[6];
    const float* Alog = (const float*)d_in[7];
    const float* nw   = (const float*)d_in[8];
    const float* Wout = (const float*)d_in[9];
    float* out = (float*)d_out;

    char* ws = (char*)d_ws;
    size_t off = 0;
    auto alloc = [&](size_t bytes) -> char* {
        char* p = ws + off;
        off += (bytes + 255) & ~(size_t)255;
        return p;
    };
    bf16*  Xb      = (bf16*)alloc((size_t)B_ * T_ * D_ * 2);          // dead after GEMMs -> onorm
    char*  wqkvt_p = alloc((size_t)CONV_DIM_ * D_ * 2);               // dead after GEMM1 -> qbuf
    bf16*  Wqkvt   = (bf16*)wqkvt_p;
    bf16*  Wzt     = (bf16*)alloc((size_t)D_ * D_ * 2);
    bf16*  Woutt   = (bf16*)alloc((size_t)D_ * D_ * 2);
    char*  mixed_p = alloc((size_t)B_ * T_ * CONV_DIM_ * 2);          // 50.3MB; dead after conv -> obuf+Araw
    bf16*  mixedb  = (bf16*)mixed_p;
    bf16*  zb      = (bf16*)alloc((size_t)B_ * T_ * D_ * 2);
    bf16*  kbuf    = (bf16*)alloc((size_t)B_ * T_ * D_ * 2);
    bf16*  vbuf    = (bf16*)alloc((size_t)B_ * T_ * D_ * 2);
    float* gbuf    = (float*)alloc((size_t)B_ * T_ * H_ * 4);
    float* bbuf    = (float*)alloc((size_t)B_ * T_ * H_ * 4);
    float* Mraw    = (float*)alloc((size_t)1024 * 4096 * 4);          // 16.8MB
    bf16*  Tg      = (bf16*)alloc((size_t)1024 * 4096 * 2);           // 8.4MB
    bf16*  Mg      = (bf16*)alloc((size_t)1024 * 4096 * 2);           // 8.4MB
    float* lamg    = (float*)alloc((size_t)1024 * 64 * 4);
    float* ratiog  = (float*)alloc((size_t)1024 * 64 * 4);
    // aliases (stream-order safe):
    bf16*  qbuf    = (bf16*)wqkvt_p;                       // conv writes after GEMM1 read
    float* obuf    = (float*)mixed_p;                      // 33.55MB, after conv read
    float* Araw    = (float*)(mixed_p + (size_t)B_ * T_ * D_ * 4);  // +33.55MB, 16.78MB = exact fit
    bf16*  onorm   = (bf16*)Xb;

    cvt_bf16_kernel<<<dim3((B_ * T_ * D_ / 4 + 255) / 256), dim3(256), 0, stream>>>(X, Xb, B_ * T_ * D_ / 4);
    transpose_kernel<<<dim3(CONV_DIM_ / 32, D_ / 32), dim3(256), 0, stream>>>(Wqkv, Wqkvt, D_, CONV_DIM_);
    transpose_kernel<<<dim3(D_ / 32, D_ / 32), dim3(256), 0, stream>>>(Wz, Wzt, D_, D_);
    transpose_kernel<<<dim3(D_ / 32, D_ / 32), dim3(256), 0, stream>>>(Wout, Woutt, D_, D_);

    gemm_kernel<bf16><<<dim3(CONV_DIM_ / 128, B_ * T_ / 128), dim3(256), 0, stream>>>(
        Xb, Wqkvt, mixedb, B_ * T_, CONV_DIM_, D_);
    gemm_kernel<bf16><<<dim3(D_ / 128, B_ * T_ / 128), dim3(256), 0, stream>>>(
        Xb, Wzt, zb, B_ * T_, D_, D_);

    gbeta_kernel<<<dim3(B_ * T_), dim3(64), 0, stream>>>(X, Wb, Wa, dtb, Alog, gbuf, bbuf);
    conv_silu_kernel<<<dim3(CONV_DIM_ / 128, B_ * T_), dim3(128), 0, stream>>>(mixedb, cw, qbuf, kbuf, vbuf);

    qkkt_kernel<<<dim3(1024), dim3(256), 0, stream>>>(qbuf, kbuf, Araw, Mraw);
    prep_kernel<<<dim3(1024), dim3(64), 0, stream>>>(gbuf, bbuf, Araw, Mraw, lamg, ratiog, Tg, Mg);
    seq_kernel<<<dim3(128), dim3(256), 0, stream>>>(qbuf, kbuf, vbuf, Tg, Mg, lamg, ratiog, bbuf, obuf);

    gated_norm_kernel<<<dim3(B_ * T_ * H_), dim3(64), 0, stream>>>(obuf, zb, nw, onorm);

    gemm_kernel<float><<<dim3(D_ / 128, B_ * T_ / 128), dim3(256), 0, stream>>>(
        onorm, Woutt, out, B_ * T_, D_, D_);
}

// Round 5
// 720.107 us; speedup vs baseline: 3.2374x; 1.0681x over previous
//
#include <hip/hip_runtime.h>

#define B_ 2
#define T_ 2048
#define D_ 2048
#define H_ 16
#define CONV_DIM_ 6144
#define NC_ 32   // chunks per sequence
#define CK_ 64   // chunk length

typedef __bf16 bf16;
typedef bf16 bf16x8 __attribute__((ext_vector_type(8)));
typedef bf16 bf16x4 __attribute__((ext_vector_type(4)));
typedef float floatx4 __attribute__((ext_vector_type(4)));

// async global->LDS 16B per lane: dest = wave-uniform base + lane*16
__device__ __forceinline__ void async_copy16(bf16* lds, const bf16* g) {
    auto* g1 = (const __attribute__((address_space(1))) unsigned int*)g;
    auto* l3 = (__attribute__((address_space(3))) unsigned int*)lds;
    __builtin_amdgcn_global_load_lds(g1, l3, 16, 0, 0);
}

// ---------------- elementwise f32 -> bf16 ----------------
__global__ void cvt_bf16_kernel(const float* __restrict__ in, bf16* __restrict__ out, int n4) {
    int i = blockIdx.x * 256 + threadIdx.x;
    if (i < n4) {
        float4 v = ((const float4*)in)[i];
        bf16x4 o = { (bf16)v.x, (bf16)v.y, (bf16)v.z, (bf16)v.w };
        *(bf16x4*)(out + 4 * (size_t)i) = o;
    }
}

// ---------------- transpose f32 [R,Cn] -> bf16 [Cn,R] ----------------
__global__ void transpose_kernel(const float* __restrict__ in, bf16* __restrict__ out, int R, int Cn) {
    __shared__ float tile[32][33];
    const int c0 = blockIdx.x << 5, r0 = blockIdx.y << 5;
    const int tx = threadIdx.x & 31, ty = threadIdx.x >> 5;
#pragma unroll
    for (int i = 0; i < 4; ++i) {
        int r = ty + (i << 3);
        tile[r][tx] = in[(size_t)(r0 + r) * Cn + c0 + tx];
    }
    __syncthreads();
#pragma unroll
    for (int i = 0; i < 4; ++i) {
        int cc = ty + (i << 3);
        out[(size_t)(c0 + cc) * R + r0 + tx] = (bf16)tile[tx][cc];
    }
}

// ---------------- Wb[2048,16],Wa[2048,16] -> Wba bf16 [32][2048] ----------------
__global__ void wba_cvt_kernel(const float* __restrict__ Wb, const float* __restrict__ Wa,
                               bf16* __restrict__ Wba) {
    int idx = blockIdx.x * 256 + threadIdx.x;  // 32768
    int d = idx >> 4, h = idx & 15;
    Wba[(size_t)h * 2048 + d]        = (bf16)Wb[idx];
    Wba[(size_t)(h + 16) * 2048 + d] = (bf16)Wa[idx];
}

// ---------------- bf16 MFMA GEMM: A[M,K] x Bt[N,K] -> C[M,N] ----------------
// 128x128 tile, 4 waves, BK=64, XOR-swizzled LDS, global_load_lds staging (m97).
template <typename OutT>
__global__ __launch_bounds__(256) void gemm_kernel(
    const bf16* __restrict__ A, const bf16* __restrict__ Bt, OutT* __restrict__ C,
    int M, int N, int K) {
    __shared__ bf16 As[128 * 64];
    __shared__ bf16 Bs[128 * 64];
    const int tid = threadIdx.x;
    const int m0 = blockIdx.y << 7;
    const int n0 = blockIdx.x << 7;
    const int wave = tid >> 6, lane = tid & 63;
    const int wm = (wave >> 1) << 6, wn = (wave & 1) << 6;
    const int lrow = lane & 15, quad = lane >> 4;
    // lane -> (row-in-8, swizzled col unit): LDS dest is base+lane*16, so pick
    // the global column so the XOR-swizzled layout lands correctly.
    const int rl = lane >> 3;
    const int c8s = (lane & 7) ^ (rl & 7);

    floatx4 acc[4][4];
#pragma unroll
    for (int mt = 0; mt < 4; ++mt)
#pragma unroll
        for (int nt = 0; nt < 4; ++nt)
            acc[mt][nt] = floatx4{0.f, 0.f, 0.f, 0.f};

    for (int k0 = 0; k0 < K; k0 += 64) {
        __syncthreads();
#pragma unroll
        for (int i = 0; i < 4; ++i) {
            const int slot = wave * 4 + i;           // 16 slots of 8 rows
            const int r = slot * 8 + rl;
            async_copy16(&As[slot * 512], A + (size_t)(m0 + r) * K + k0 + c8s * 8);
            async_copy16(&Bs[slot * 512], Bt + (size_t)(n0 + r) * K + k0 + c8s * 8);
        }
        __syncthreads();
#pragma unroll
        for (int kk = 0; kk < 64; kk += 32) {
            const int sw = (((kk >> 3) + quad) ^ (lrow & 7)) << 3;
            bf16x8 af[4], bfr[4];
#pragma unroll
            for (int mt = 0; mt < 4; ++mt) {
                af[mt]  = *(const bf16x8*)(&As[((wm + (mt << 4) + lrow) << 6) + sw]);
                bfr[mt] = *(const bf16x8*)(&Bs[((wn + (mt << 4) + lrow) << 6) + sw]);
            }
#pragma unroll
            for (int mt = 0; mt < 4; ++mt)
#pragma unroll
                for (int nt = 0; nt < 4; ++nt)
                    acc[mt][nt] = __builtin_amdgcn_mfma_f32_16x16x32_bf16(af[mt], bfr[nt], acc[mt][nt], 0, 0, 0);
        }
    }
#pragma unroll
    for (int mt = 0; mt < 4; ++mt)
#pragma unroll
        for (int nt = 0; nt < 4; ++nt) {
            const int col = n0 + wn + (nt << 4) + lrow;
            const int rowb = m0 + wm + (mt << 4) + (quad << 2);
#pragma unroll
            for (int i2 = 0; i2 < 4; ++i2)
                C[(size_t)(rowb + i2) * N + col] = (OutT)acc[mt][nt][i2];
        }
}

// ---------------- depthwise causal conv (K=4) + silu + split + l2norm -> bf16 ----------------
__global__ void conv_silu_kernel(const bf16* __restrict__ mixed, const float* __restrict__ cw,
                                 bf16* __restrict__ qb, bf16* __restrict__ kb, bf16* __restrict__ vb) {
    const int s = blockIdx.x;
    const int bt = blockIdx.y;
    const int t = bt & (T_ - 1);
    const int b = bt >> 11;
    const int c = (s << 7) + threadIdx.x;
    const size_t base = (size_t)bt * CONV_DIM_ + c;
    const float w0 = cw[c * 4], w1 = cw[c * 4 + 1], w2 = cw[c * 4 + 2], w3 = cw[c * 4 + 3];
    float acc = (float)mixed[base] * w3;
    if (t >= 1) acc += (float)mixed[base - CONV_DIM_] * w2;
    if (t >= 2) acc += (float)mixed[base - 2 * CONV_DIM_] * w1;
    if (t >= 3) acc += (float)mixed[base - 3 * CONV_DIM_] * w0;
    const float val = acc / (1.f + __expf(-acc));  // silu

    __shared__ float red[2];
    if (s < 32) {
        float ss = val * val;
#pragma unroll
        for (int o = 1; o < 64; o <<= 1) ss += __shfl_xor(ss, o);
        if ((threadIdx.x & 63) == 0) red[threadIdx.x >> 6] = ss;
        __syncthreads();
        const float scale = rsqrtf(red[0] + red[1] + 1e-6f);
        const int h = s & 15;
        const size_t oidx = (((size_t)(b * H_ + h)) * T_ + t) * 128 + threadIdx.x;
        if (s < 16) qb[oidx] = (bf16)(val * scale * 0.08838834764831845f);
        else        kb[oidx] = (bf16)(val * scale);
    } else {
        const int h = s - 32;
        const size_t oidx = (((size_t)(b * H_ + h)) * T_ + t) * 128 + threadIdx.x;
        vb[oidx] = (bf16)val;
    }
}

// ---------------- beta/g via skinny MFMA: [4096x2048] @ Wba^T[2048x32] ----------------
__global__ __launch_bounds__(256) void gbeta_mfma_kernel(
    const bf16* __restrict__ Xb, const bf16* __restrict__ Wba,
    const float* __restrict__ dtb, const float* __restrict__ Alog,
    float* __restrict__ gbuf, float* __restrict__ bbuf) {
    const int tid = threadIdx.x, wave = tid >> 6, lane = tid & 63;
    const int ln = lane & 15, qd = lane >> 4;
    const int m0 = blockIdx.x * 64 + wave * 16;
    floatx4 acc0 = {0.f, 0.f, 0.f, 0.f}, acc1 = {0.f, 0.f, 0.f, 0.f};
    const bf16* arow = Xb + (size_t)(m0 + ln) * 2048 + qd * 8;
    const bf16* b0 = Wba + (size_t)ln * 2048 + qd * 8;
    const bf16* b1 = Wba + (size_t)(16 + ln) * 2048 + qd * 8;
    for (int k = 0; k < 2048; k += 32) {
        bf16x8 af  = *(const bf16x8*)(arow + k);
        bf16x8 bf0 = *(const bf16x8*)(b0 + k);
        bf16x8 bf1 = *(const bf16x8*)(b1 + k);
        acc0 = __builtin_amdgcn_mfma_f32_16x16x32_bf16(af, bf0, acc0, 0, 0, 0);
        acc1 = __builtin_amdgcn_mfma_f32_16x16x32_bf16(af, bf1, acc1, 0, 0, 0);
    }
    const float dtbv = dtb[ln], al = __expf(Alog[ln]);
#pragma unroll
    for (int ii = 0; ii < 4; ++ii) {
        const int row = m0 + qd * 4 + ii;  // bt
        const int t = row & (T_ - 1), b = row >> 11;
        const size_t o = ((size_t)(b * H_ + ln)) * T_ + t;
        bbuf[o] = 1.f / (1.f + __expf(-acc0[ii]));
        const float xx = acc1[ii] + dtbv;
        const float sp = (xx > 15.f) ? xx : log1pf(__expf(xx));
        gbuf[o] = -al * sp;
    }
}

// ---------------- chunked delta rule: precompute 1 — KK^T and QK^T ----------------
__global__ __launch_bounds__(256) void qkkt_kernel(const bf16* __restrict__ qb, const bf16* __restrict__ kb,
                                                   float* __restrict__ Araw, float* __restrict__ Mraw) {
    const int u = blockIdx.x;
    const int bh = u >> 5, nc = u & 31;
    const int t0 = nc * CK_;
    const int tid = threadIdx.x, wave = tid >> 6, lane = tid & 63;
    const int qd = lane >> 4, ln = lane & 15;
    __shared__ bf16 Kc[64 * 136], Qc[64 * 136];
    const size_t kbase = ((size_t)bh * T_ + t0) * 128;
#pragma unroll
    for (int it = 0; it < 4; ++it) {
        int idx = it * 256 + tid;
        int row = idx >> 4, c8 = idx & 15;
        *(uint4*)(&Kc[row * 136 + c8 * 8]) = *(const uint4*)(kb + kbase + row * 128 + c8 * 8);
        *(uint4*)(&Qc[row * 136 + c8 * 8]) = *(const uint4*)(qb + kbase + row * 128 + c8 * 8);
    }
    __syncthreads();
#pragma unroll
    for (int nt = 0; nt < 4; ++nt) {
        floatx4 accA = {0.f, 0.f, 0.f, 0.f}, accM = {0.f, 0.f, 0.f, 0.f};
#pragma unroll
        for (int kk = 0; kk < 4; ++kk) {
            bf16x8 bfr = *(const bf16x8*)(&Kc[(nt * 16 + ln) * 136 + kk * 32 + qd * 8]);
            bf16x8 afK = *(const bf16x8*)(&Kc[(wave * 16 + ln) * 136 + kk * 32 + qd * 8]);
            bf16x8 afQ = *(const bf16x8*)(&Qc[(wave * 16 + ln) * 136 + kk * 32 + qd * 8]);
            accA = __builtin_amdgcn_mfma_f32_16x16x32_bf16(afK, bfr, accA, 0, 0, 0);
            accM = __builtin_amdgcn_mfma_f32_16x16x32_bf16(afQ, bfr, accM, 0, 0, 0);
        }
#pragma unroll
        for (int ii = 0; ii < 4; ++ii) {
            int i = wave * 16 + qd * 4 + ii, j = nt * 16 + ln;
            Araw[(size_t)u * 4096 + i * 64 + j] = accA[ii];
            Mraw[(size_t)u * 4096 + i * 64 + j] = accM[ii];
        }
    }
}

// ---------------- precompute 2 — decay vectors, T = (I+A)^{-1}, masked M ----------------
__global__ __launch_bounds__(64) void prep_kernel(
    const float* __restrict__ gbuf, const float* __restrict__ bbuf,
    const float* __restrict__ Araw, const float* __restrict__ Mraw,
    float* __restrict__ lamg, float* __restrict__ ratiog,
    bf16* __restrict__ Tg, bf16* __restrict__ Mg) {
    const int u = blockIdx.x, bh = u >> 5, nc = u & 31, t0 = nc * CK_;
    const int lane = threadIdx.x;
    __shared__ float L[64 * 65];
    __shared__ float cv[64], bv[64];
    float g = gbuf[(size_t)bh * T_ + t0 + lane];
    float beta = bbuf[(size_t)bh * T_ + t0 + lane];
    float c = g;
#pragma unroll
    for (int off = 1; off < 64; off <<= 1) {
        float tval = __shfl_up(c, off);
        if (lane >= off) c += tval;
    }
    float c63 = __shfl(c, 63);
    lamg[(size_t)u * 64 + lane] = __expf(c);
    ratiog[(size_t)u * 64 + lane] = __expf(c63 - c);
    cv[lane] = c; bv[lane] = beta;
    __syncthreads();
    for (int i = 0; i < 64; ++i) {
        float a = Araw[(size_t)u * 4096 + i * 64 + lane];
        L[i * 65 + lane] = (lane < i) ? bv[i] * __expf(cv[i] - c) * a : 0.f;
    }
    __syncthreads();
    float t[64];
#pragma unroll
    for (int i = 0; i < 64; ++i) t[i] = (i == lane) ? 1.f : 0.f;
#pragma unroll
    for (int j = 0; j < 63; ++j) {
#pragma unroll
        for (int i = j + 1; i < 64; ++i)
            t[i] -= L[i * 65 + j] * t[j];
    }
#pragma unroll
    for (int i = 0; i < 64; ++i)
        Tg[(size_t)u * 4096 + i * 64 + lane] = (bf16)t[i];
    for (int i = 0; i < 64; ++i) {
        float m = Mraw[(size_t)u * 4096 + i * 64 + lane];
        float mij = (lane <= i) ? __expf(cv[i] - c) * m : 0.f;
        Mg[(size_t)u * 4096 + i * 64 + lane] = (bf16)mij;
    }
}

// ---------------- sequential chunk loop ----------------
// 256 blocks = 8 v-splits (dv=16) x 32 bh; blk = vs*32+bh so all v-splits of a
// bh share an XCD (blk%8 == bh%8) -> L2 reuse of T/M/K/Q. K/Q MFMA A-fragments
// loaded straight from global into regs; next chunk fully register-prefetched.
struct Pref {
    uint4 t2[2], m2[2], k4[4];
    bf16x8 kf[4], qf[4];
    float rr[4], vv[4], lam[4], bet[4], lamlast;
};

__device__ __forceinline__ void load_pref(
    Pref& p, int u, int t0, size_t kbase, int tid, int wave, int ln, int qd,
    int bh, int vbase,
    const bf16* __restrict__ qb, const bf16* __restrict__ kb, const bf16* __restrict__ vb,
    const bf16* __restrict__ Tg, const bf16* __restrict__ Mg,
    const float* __restrict__ lamg, const float* __restrict__ ratiog,
    const float* __restrict__ bbuf) {
#pragma unroll
    for (int it = 0; it < 2; ++it) {
        int idx = it * 256 + tid;
        int row = idx >> 3, c8 = idx & 7;
        p.t2[it] = *(const uint4*)(Tg + (size_t)u * 4096 + row * 64 + c8 * 8);
        p.m2[it] = *(const uint4*)(Mg + (size_t)u * 4096 + row * 64 + c8 * 8);
    }
#pragma unroll
    for (int it = 0; it < 4; ++it) {
        int idx = it * 256 + tid;
        int row = idx >> 4, c8 = idx & 15;
        p.k4[it] = *(const uint4*)(kb + kbase + (size_t)row * 128 + c8 * 8);
        p.rr[it] = ratiog[(size_t)u * 64 + row];
    }
    const size_t rowoff = kbase + (size_t)(wave * 16 + ln) * 128;
#pragma unroll
    for (int kk = 0; kk < 4; ++kk) {
        p.kf[kk] = *(const bf16x8*)(kb + rowoff + kk * 32 + qd * 8);
        p.qf[kk] = *(const bf16x8*)(qb + rowoff + kk * 32 + qd * 8);
    }
    const int i0 = wave * 16 + qd * 4;
#pragma unroll
    for (int ii = 0; ii < 4; ++ii) {
        p.vv[ii]  = (float)vb[kbase + (size_t)(i0 + ii) * 128 + vbase + ln];
        p.lam[ii] = lamg[(size_t)u * 64 + i0 + ii];
        p.bet[ii] = bbuf[(size_t)bh * T_ + t0 + i0 + ii];
    }
    p.lamlast = lamg[(size_t)u * 64 + 63];
}

__global__ __launch_bounds__(256) void seq_kernel(
    const bf16* __restrict__ qb, const bf16* __restrict__ kb, const bf16* __restrict__ vb,
    const bf16* __restrict__ Tg, const bf16* __restrict__ Mg,
    const float* __restrict__ lamg, const float* __restrict__ ratiog,
    const float* __restrict__ bbuf, float* __restrict__ ob) {
    const int bh = blockIdx.x & 31;
    const int vs = blockIdx.x >> 5;
    const int vbase = vs * 16;
    const int tid = threadIdx.x;
    const int wave = tid >> 6, lane = tid & 63;
    const int qd = lane >> 4, ln = lane & 15;

    __shared__ bf16 Ktp[128 * 72];
    __shared__ bf16 Tt[64 * 72], Mm[64 * 72];
    __shared__ bf16 bT[16 * 72], Dt[16 * 72];
    __shared__ bf16 Sbf[16 * 136];
    __shared__ float Sf[16 * 132];

    for (int idx = tid; idx < 16 * 132; idx += 256) Sf[idx] = 0.f;
    for (int idx = tid; idx < 16 * 136; idx += 256) Sbf[idx] = (bf16)0.f;

    Pref cur, nxt;
    load_pref(cur, bh * NC_, 0, (size_t)bh * T_ * 128, tid, wave, ln, qd, bh, vbase,
              qb, kb, vb, Tg, Mg, lamg, ratiog, bbuf);
    __syncthreads();

    for (int nc = 0; nc < NC_; ++nc) {
        const int t0 = nc * CK_;
        const size_t kbase = ((size_t)bh * T_ + t0) * 128;
        const int u = bh * NC_ + nc;
        (void)u;

        // stage LDS from cur regs
#pragma unroll
        for (int it = 0; it < 2; ++it) {
            int idx = it * 256 + tid;
            int row = idx >> 3, c8 = idx & 7;
            *(uint4*)(&Tt[row * 72 + c8 * 8]) = cur.t2[it];
            *(uint4*)(&Mm[row * 72 + c8 * 8]) = cur.m2[it];
        }
#pragma unroll
        for (int it = 0; it < 4; ++it) {
            int idx = it * 256 + tid;
            int row = idx >> 4, c8 = idx & 15;
            bf16 tmp[8]; *(uint4*)tmp = cur.k4[it];
#pragma unroll
            for (int cc = 0; cc < 8; ++cc)
                Ktp[(c8 * 8 + cc) * 72 + row] = (bf16)((float)tmp[cc] * cur.rr[it]);
        }
        __syncthreads();  // B0

        // prefetch next chunk into regs (drained at B1; stage1 covers part)
        {
            const int ncn = (nc + 1 < NC_) ? nc + 1 : nc;
            load_pref(nxt, bh * NC_ + ncn, ncn * CK_, ((size_t)bh * T_ + (size_t)ncn * CK_) * 128,
                      tid, wave, ln, qd, bh, vbase, qb, kb, vb, Tg, Mg, lamg, ratiog, bbuf);
        }

        // stage 1: KS = K @ S -> C(row i = wave*16+qd*4.., col v = ln)
        floatx4 ks = {0.f, 0.f, 0.f, 0.f};
#pragma unroll
        for (int kk = 0; kk < 4; ++kk) {
            bf16x8 bf = *(const bf16x8*)(&Sbf[ln * 136 + kk * 32 + qd * 8]);
            ks = __builtin_amdgcn_mfma_f32_16x16x32_bf16(cur.kf[kk], bf, ks, 0, 0, 0);
        }
        // stage 2: b = beta*(V - lam*KS) -> bT[v][i]
        {
            const int i0 = wave * 16 + qd * 4;
            bf16x4 bw;
#pragma unroll
            for (int ii = 0; ii < 4; ++ii)
                bw[ii] = (bf16)(cur.bet[ii] * (cur.vv[ii] - cur.lam[ii] * ks[ii]));
            *(bf16x4*)(&bT[ln * 72 + i0]) = bw;
        }
        __syncthreads();  // B1

        // stage 3: D = T @ b -> Dt[v][i]
        {
            floatx4 acc = {0.f, 0.f, 0.f, 0.f};
#pragma unroll
            for (int kk = 0; kk < 2; ++kk) {
                bf16x8 af = *(const bf16x8*)(&Tt[(wave * 16 + ln) * 72 + kk * 32 + qd * 8]);
                bf16x8 bf = *(const bf16x8*)(&bT[ln * 72 + kk * 32 + qd * 8]);
                acc = __builtin_amdgcn_mfma_f32_16x16x32_bf16(af, bf, acc, 0, 0, 0);
            }
            const int i0 = wave * 16 + qd * 4;
            bf16x4 dw = { (bf16)acc[0], (bf16)acc[1], (bf16)acc[2], (bf16)acc[3] };
            *(bf16x4*)(&Dt[ln * 72 + i0]) = dw;
        }
        __syncthreads();  // B2

        // stage 4: O = lam ⊙ (Q@S) + M@D -> global
        {
            floatx4 acc = {0.f, 0.f, 0.f, 0.f};
#pragma unroll
            for (int kk = 0; kk < 4; ++kk) {
                bf16x8 bf = *(const bf16x8*)(&Sbf[ln * 136 + kk * 32 + qd * 8]);
                acc = __builtin_amdgcn_mfma_f32_16x16x32_bf16(cur.qf[kk], bf, acc, 0, 0, 0);
            }
            floatx4 o;
#pragma unroll
            for (int ii = 0; ii < 4; ++ii) o[ii] = acc[ii] * cur.lam[ii];
#pragma unroll
            for (int kk = 0; kk < 2; ++kk) {
                bf16x8 af = *(const bf16x8*)(&Mm[(wave * 16 + ln) * 72 + kk * 32 + qd * 8]);
                bf16x8 bf = *(const bf16x8*)(&Dt[ln * 72 + kk * 32 + qd * 8]);
                o = __builtin_amdgcn_mfma_f32_16x16x32_bf16(af, bf, o, 0, 0, 0);
            }
            const int i0 = wave * 16 + qd * 4;
#pragma unroll
            for (int ii = 0; ii < 4; ++ii)
                ob[kbase + (size_t)(i0 + ii) * 128 + vbase + ln] = o[ii];
        }
        // stage 5: S = lamlast*S + K'^T @ D (exclusive (v,kd) cells per lane)
#pragma unroll
        for (int mt = 0; mt < 2; ++mt) {
            const int kt = wave * 2 + mt;
            floatx4 acc = {0.f, 0.f, 0.f, 0.f};
#pragma unroll
            for (int kk = 0; kk < 2; ++kk) {
                bf16x8 af = *(const bf16x8*)(&Ktp[(kt * 16 + ln) * 72 + kk * 32 + qd * 8]);
                bf16x8 bf = *(const bf16x8*)(&Dt[ln * 72 + kk * 32 + qd * 8]);
                acc = __builtin_amdgcn_mfma_f32_16x16x32_bf16(af, bf, acc, 0, 0, 0);
            }
            const int k0 = kt * 16 + qd * 4;
            floatx4 sold = *(floatx4*)(&Sf[ln * 132 + k0]);
#pragma unroll
            for (int ii = 0; ii < 4; ++ii) sold[ii] = sold[ii] * cur.lamlast + acc[ii];
            *(floatx4*)(&Sf[ln * 132 + k0]) = sold;
        }
        __syncthreads();  // B3
        // refresh Sbf from Sf
        {
            const int vloc = tid >> 4, k0 = (tid & 15) * 8;
            floatx4 s0 = *(floatx4*)(&Sf[vloc * 132 + k0]);
            floatx4 s1 = *(floatx4*)(&Sf[vloc * 132 + k0 + 4]);
            bf16x8 sb = { (bf16)s0[0], (bf16)s0[1], (bf16)s0[2], (bf16)s0[3],
                          (bf16)s1[0], (bf16)s1[1], (bf16)s1[2], (bf16)s1[3] };
            *(bf16x8*)(&Sbf[vloc * 136 + k0]) = sb;
        }
        __syncthreads();  // B4
        cur = nxt;
    }
}

// ---------------- o = o*silu(z); RMSNorm over DV; -> bf16 ----------------
__global__ void gated_norm_kernel(const float* __restrict__ ob, const bf16* __restrict__ z,
                                  const float* __restrict__ nw, bf16* __restrict__ onorm) {
    const int idx = blockIdx.x;  // B*T*H
    const int h = idx & (H_ - 1);
    const int bt = idx >> 4;
    const int t = bt & (T_ - 1);
    const int b = bt >> 11;
    const int tid = threadIdx.x;  // 64
    const size_t obase = (((size_t)(b * H_ + h)) * T_ + t) * 128;
    const size_t zbase = (size_t)bt * 2048 + (h << 7);
    float o1 = ob[obase + tid], o2 = ob[obase + tid + 64];
    const float z1 = (float)z[zbase + tid], z2 = (float)z[zbase + tid + 64];
    o1 *= z1 / (1.f + __expf(-z1));
    o2 *= z2 / (1.f + __expf(-z2));
    float ss = o1 * o1 + o2 * o2;
#pragma unroll
    for (int o = 1; o < 64; o <<= 1) ss += __shfl_xor(ss, o);
    const float scale = rsqrtf(ss * (1.f / 128.f) + 1e-6f);
    onorm[zbase + tid]      = (bf16)(o1 * scale * nw[tid]);
    onorm[zbase + tid + 64] = (bf16)(o2 * scale * nw[tid + 64]);
}

extern "C" void kernel_launch(void* const* d_in, const int* in_sizes, int n_in,
                              void* d_out, int out_size, void* d_ws, size_t ws_size,
                              hipStream_t stream) {
    const float* X    = (const float*)d_in[0];
    const float* Wqkv = (const float*)d_in[1];
    const float* cw   = (const float*)d_in[2];
    const float* Wz   = (const float*)d_in[3];
    const float* Wb   = (const float*)d_in[4];
    const float* Wa   = (const float*)d_in[5];
    const float* dtb  = (const float*)d_in[6];
    const float* Alog = (const float*)d_in[7];
    const float* nw   = (const float*)d_in[8];
    const float* Wout = (const float*)d_in[9];
    float* out = (float*)d_out;

    char* ws = (char*)d_ws;
    size_t off = 0;
    auto alloc = [&](size_t bytes) -> char* {
        char* p = ws + off;
        off += (bytes + 255) & ~(size_t)255;
        return p;
    };
    bf16*  Xb      = (bf16*)alloc((size_t)B_ * T_ * D_ * 2);
    char*  wqkvt_p = alloc((size_t)CONV_DIM_ * D_ * 2);
    bf16*  Wqkvt   = (bf16*)wqkvt_p;
    bf16*  Wzt     = (bf16*)alloc((size_t)D_ * D_ * 2);
    bf16*  Woutt   = (bf16*)alloc((size_t)D_ * D_ * 2);
    bf16*  Wba     = (bf16*)alloc((size_t)32 * 2048 * 2);
    char*  mixed_p = alloc((size_t)B_ * T_ * CONV_DIM_ * 2);
    bf16*  mixedb  = (bf16*)mixed_p;
    bf16*  zb      = (bf16*)alloc((size_t)B_ * T_ * D_ * 2);
    bf16*  kbuf    = (bf16*)alloc((size_t)B_ * T_ * D_ * 2);
    bf16*  vbuf    = (bf16*)alloc((size_t)B_ * T_ * D_ * 2);
    float* gbuf    = (float*)alloc((size_t)B_ * T_ * H_ * 4);
    float* bbuf    = (float*)alloc((size_t)B_ * T_ * H_ * 4);
    float* Mraw    = (float*)alloc((size_t)1024 * 4096 * 4);
    bf16*  Tg      = (bf16*)alloc((size_t)1024 * 4096 * 2);
    bf16*  Mg      = (bf16*)alloc((size_t)1024 * 4096 * 2);
    float* lamg    = (float*)alloc((size_t)1024 * 64 * 4);
    float* ratiog  = (float*)alloc((size_t)1024 * 64 * 4);
    // aliases (stream-order safe):
    bf16*  qbuf    = (bf16*)wqkvt_p;
    float* obuf    = (float*)mixed_p;
    float* Araw    = (float*)(mixed_p + (size_t)B_ * T_ * D_ * 4);
    bf16*  onorm   = (bf16*)Xb;

    cvt_bf16_kernel<<<dim3((B_ * T_ * D_ / 4 + 255) / 256), dim3(256), 0, stream>>>(X, Xb, B_ * T_ * D_ / 4);
    transpose_kernel<<<dim3(CONV_DIM_ / 32, D_ / 32), dim3(256), 0, stream>>>(Wqkv, Wqkvt, D_, CONV_DIM_);
    transpose_kernel<<<dim3(D_ / 32, D_ / 32), dim3(256), 0, stream>>>(Wz, Wzt, D_, D_);
    transpose_kernel<<<dim3(D_ / 32, D_ / 32), dim3(256), 0, stream>>>(Wout, Woutt, D_, D_);
    wba_cvt_kernel<<<dim3(128), dim3(256), 0, stream>>>(Wb, Wa, Wba);

    gemm_kernel<bf16><<<dim3(CONV_DIM_ / 128, B_ * T_ / 128), dim3(256), 0, stream>>>(
        Xb, Wqkvt, mixedb, B_ * T_, CONV_DIM_, D_);
    gemm_kernel<bf16><<<dim3(D_ / 128, B_ * T_ / 128), dim3(256), 0, stream>>>(
        Xb, Wzt, zb, B_ * T_, D_, D_);

    gbeta_mfma_kernel<<<dim3(64), dim3(256), 0, stream>>>(Xb, Wba, dtb, Alog, gbuf, bbuf);
    conv_silu_kernel<<<dim3(CONV_DIM_ / 128, B_ * T_), dim3(128), 0, stream>>>(mixedb, cw, qbuf, kbuf, vbuf);

    qkkt_kernel<<<dim3(1024), dim3(256), 0, stream>>>(qbuf, kbuf, Araw, Mraw);
    prep_kernel<<<dim3(1024), dim3(64), 0, stream>>>(gbuf, bbuf, Araw, Mraw, lamg, ratiog, Tg, Mg);
    seq_kernel<<<dim3(256), dim3(256), 0, stream>>>(qbuf, kbuf, vbuf, Tg, Mg, lamg, ratiog, bbuf, obuf);

    gated_norm_kernel<<<dim3(B_ * T_ * H_), dim3(64), 0, stream>>>(obuf, zb, nw, onorm);

    gemm_kernel<float><<<dim3(D_ / 128, B_ * T_ / 128), dim3(256), 0, stream>>>(
        onorm, Woutt, out, B_ * T_, D_, D_);
}